// Round 1
// baseline (678.686 us; speedup 1.0000x reference)
//
#include <hip/hip_runtime.h>
#include <math.h>

#define NN 4096
#define FIN 512
#define HH 8
#define DD 64

typedef unsigned long long u64;

// ---------- Kernel 1: bit-pack adjacency: bm[i][jw] (u64, bit j%64) ----------
__global__ __launch_bounds__(256) void k_bitpack(const int* __restrict__ adj,
                                                 u64* __restrict__ bm) {
    int tid = blockIdx.x * 256 + threadIdx.x;   // one thread per adj element
    int lane = threadIdx.x & 63;
    int v = adj[tid];
    u64 m = __ballot(v > 0);
    if (lane == 0) bm[tid >> 6] = m;
}

// ---------- Kernel 2: projection GEMM fp32: Wh[h][n][d] = sum_f x[n][f] W[h][f][d] ----------
// block = (n-tile of 64, head). 256 threads: tx=tid&15 -> 4 d's, ty=tid>>4 -> 4 i's.
__global__ __launch_bounds__(256) void k_proj(const float* __restrict__ x,
                                              const float* __restrict__ W,
                                              float* __restrict__ Wh) {
    __shared__ float xs[32][68];   // [k][i] (transposed so reads are float4)
    __shared__ float ws[32][68];   // [k][d]
    int h = blockIdx.y;
    int i0 = blockIdx.x * 64;
    int tid = threadIdx.x;
    int tx = tid & 15, ty = tid >> 4;
    const float* Wp = W + (size_t)h * FIN * DD;
    float acc[4][4] = {};
    for (int k0 = 0; k0 < FIN; k0 += 32) {
        #pragma unroll
        for (int e = 0; e < 8; ++e) {
            int lin = e * 256 + tid;
            int r = lin >> 5, c = lin & 31;          // r: i 0..63, c: k 0..31
            xs[c][r] = x[(size_t)(i0 + r) * FIN + k0 + c];
        }
        #pragma unroll
        for (int e = 0; e < 8; ++e) {
            int lin = e * 256 + tid;
            int r = lin >> 6, c = lin & 63;          // r: k 0..31, c: d 0..63
            ws[r][c] = Wp[(size_t)(k0 + r) * DD + c];
        }
        __syncthreads();
        #pragma unroll
        for (int kk = 0; kk < 32; ++kk) {
            float4 xv = *(const float4*)&xs[kk][ty * 4];
            float4 wv = *(const float4*)&ws[kk][tx * 4];
            float xa[4] = {xv.x, xv.y, xv.z, xv.w};
            float wa[4] = {wv.x, wv.y, wv.z, wv.w};
            #pragma unroll
            for (int ii = 0; ii < 4; ++ii)
                #pragma unroll
                for (int dd = 0; dd < 4; ++dd)
                    acc[ii][dd] += xa[ii] * wa[dd];
        }
        __syncthreads();
    }
    #pragma unroll
    for (int ii = 0; ii < 4; ++ii) {
        float4 v = make_float4(acc[ii][0], acc[ii][1], acc[ii][2], acc[ii][3]);
        *(float4*)&Wh[((size_t)h * NN + i0 + ty * 4 + ii) * DD + tx * 4] = v;
    }
}

// ---------- Kernel 3: s,t — one wave per (h,n) row, lane = d ----------
__global__ __launch_bounds__(256) void k_st(const float* __restrict__ Wh,
                                            const float* __restrict__ a_src,
                                            const float* __restrict__ a_dst,
                                            float* __restrict__ s, float* __restrict__ t) {
    int gid = blockIdx.x * 256 + threadIdx.x;
    int lane = gid & 63;
    int row = gid >> 6;            // h*N + n
    int h = row >> 12;             // row / N
    float wv = Wh[(size_t)row * DD + lane];
    float sv = wv * a_src[h * DD + lane];
    float tv = wv * a_dst[h * DD + lane];
    #pragma unroll
    for (int off = 32; off; off >>= 1) {
        sv += __shfl_down(sv, off);
        tv += __shfl_down(tv, off);
    }
    if (lane == 0) { s[row] = sv; t[row] = tv; }
}

// ---------- Kernel 4: fused masked-softmax aggregation + ELU ----------
// block = (i-tile of 128, head). 256 threads: tx=tid&15 -> 4 d's, ty=tid>>4 -> 8 i's.
// out[n][h*64+d] = elu( (1/l_i) * sum_j adj_ij * exp(lrelu(s_i+t_j)) * Wh[h][j][d] )
__global__ __launch_bounds__(256) void k_agg(const float* __restrict__ Wh,
                                             const float* __restrict__ s,
                                             const float* __restrict__ t,
                                             const u64* __restrict__ bm,
                                             float* __restrict__ out) {
    __shared__ float wht[64][68];    // [j][d]
    __shared__ float wls[64][132];   // [j][i]  (transposed for float4 reads over i)
    __shared__ float tls[64];
    __shared__ u64 bmls[128];
    int h = blockIdx.y;
    int i0 = blockIdx.x * 128;
    int tid = threadIdx.x;
    int tx = tid & 15, ty = tid >> 4;
    float sreg[8];
    #pragma unroll
    for (int ii = 0; ii < 8; ++ii) sreg[ii] = s[h * NN + i0 + ty * 8 + ii];
    float acc[8][4] = {};
    float lacc[8] = {};
    for (int jt = 0; jt < NN / 64; ++jt) {
        int j0 = jt * 64;
        // --- stage Wh tile [64][64], t slice, adjacency words ---
        #pragma unroll
        for (int e = 0; e < 4; ++e) {
            int lin = e * 256 + tid;                 // 1024 float4 chunks
            int r = lin >> 4, c = (lin & 15) * 4;
            *(float4*)&wht[r][c] = *(const float4*)&Wh[((size_t)h * NN + j0 + r) * DD + c];
        }
        if (tid < 128) bmls[tid] = bm[(i0 + tid) * 64 + jt];
        else if (tid < 192) tls[tid - 128] = t[h * NN + j0 + (tid - 128)];
        __syncthreads();
        // --- edge weights: w[i][j] = bit ? exp(lrelu(s_i + t_j)) : 0 ---
        #pragma unroll
        for (int ii = 0; ii < 8; ++ii) {
            int ig = ty * 8 + ii;
            u64 bits = bmls[ig];
            float sv = sreg[ii];
            #pragma unroll
            for (int jj = 0; jj < 4; ++jj) {
                int j = tx * 4 + jj;
                float z = sv + tls[j];
                z = z > 0.f ? z : 0.2f * z;
                float wv = ((bits >> j) & 1ULL) ? __expf(z) : 0.f;
                wls[j][ig] = wv;
            }
        }
        __syncthreads();
        // --- rank-64 update: acc[i][d] += w[i][j] * Wh[j][d]; l[i] += w[i][j] ---
        #pragma unroll 8
        for (int jj = 0; jj < 64; ++jj) {
            float4 w0 = *(const float4*)&wls[jj][ty * 8];
            float4 w1 = *(const float4*)&wls[jj][ty * 8 + 4];
            float4 hv = *(const float4*)&wht[jj][tx * 4];
            float wa[8] = {w0.x, w0.y, w0.z, w0.w, w1.x, w1.y, w1.z, w1.w};
            float ha[4] = {hv.x, hv.y, hv.z, hv.w};
            #pragma unroll
            for (int ii = 0; ii < 8; ++ii) {
                lacc[ii] += wa[ii];
                #pragma unroll
                for (int dd = 0; dd < 4; ++dd)
                    acc[ii][dd] += wa[ii] * ha[dd];
            }
        }
        __syncthreads();
    }
    // --- epilogue: normalize, ELU, store out[n][h*64+d] ---
    #pragma unroll
    for (int ii = 0; ii < 8; ++ii) {
        int n = i0 + ty * 8 + ii;
        float inv = 1.0f / lacc[ii];
        float vv[4];
        #pragma unroll
        for (int dd = 0; dd < 4; ++dd) {
            float u = acc[ii][dd] * inv;
            vv[dd] = u > 0.f ? u : expm1f(u);
        }
        *(float4*)&out[(size_t)n * (HH * DD) + h * DD + tx * 4] =
            make_float4(vv[0], vv[1], vv[2], vv[3]);
    }
}

extern "C" void kernel_launch(void* const* d_in, const int* in_sizes, int n_in,
                              void* d_out, int out_size, void* d_ws, size_t ws_size,
                              hipStream_t stream) {
    const float* x     = (const float*)d_in[0];
    const int*   adj   = (const int*)d_in[1];
    const float* W     = (const float*)d_in[2];
    const float* a_src = (const float*)d_in[3];
    const float* a_dst = (const float*)d_in[4];
    float* out = (float*)d_out;

    char* ws = (char*)d_ws;
    float* Wh = (float*)ws;                                    // 8 MB
    u64*   bm = (u64*)(ws + (size_t)8 * 1024 * 1024);          // 2 MB
    float* s  = (float*)(ws + (size_t)10 * 1024 * 1024);       // 128 KB
    float* t  = (float*)(ws + (size_t)10 * 1024 * 1024 + 128 * 1024);

    k_bitpack<<<dim3(NN * NN / 256), dim3(256), 0, stream>>>(adj, bm);
    k_proj<<<dim3(NN / 64, HH), dim3(256), 0, stream>>>(x, W, Wh);
    k_st<<<dim3(HH * NN / 4), dim3(256), 0, stream>>>(Wh, a_src, a_dst, s, t);
    k_agg<<<dim3(NN / 128, HH), dim3(256), 0, stream>>>(Wh, s, t, bm, out);
}

// Round 2
// 172.372 us; speedup vs baseline: 3.9373x; 3.9373x over previous
//
#include <hip/hip_runtime.h>
#include <math.h>

#define NN 4096
#define FIN 512
#define HH 8
#define DD 64

typedef unsigned long long u64;
typedef unsigned int u32;
typedef float f32x4 __attribute__((ext_vector_type(4)));
typedef short short8 __attribute__((ext_vector_type(8)));

__device__ inline ushort bf16rne(float f) {
    u32 u = __float_as_uint(f);
    u += 0x7FFFu + ((u >> 16) & 1u);
    return (ushort)(u >> 16);
}

// ---------- Kernel 1: bit-pack adjacency: bm[i][jw] (u64, bit j%64) ----------
__global__ __launch_bounds__(256) void k_bitpack(const int* __restrict__ adj,
                                                 u64* __restrict__ bm) {
    int tid = blockIdx.x * 256 + threadIdx.x;   // one thread per adj element
    int lane = threadIdx.x & 63;
    int v = adj[tid];
    u64 m = __ballot(v > 0);
    if (lane == 0) bm[tid >> 6] = m;
}

// ---------- Kernel 2: projection GEMM fp32 -> bf16 Whb + fused s,t ----------
// block = (n-tile of 64, head). 256 threads: tx=tid&15 -> 4 d's, ty=tid>>4 -> 4 i's.
__global__ __launch_bounds__(256) void k_proj(const float* __restrict__ x,
                                              const float* __restrict__ W,
                                              const float* __restrict__ a_src,
                                              const float* __restrict__ a_dst,
                                              ushort* __restrict__ Whb,
                                              float* __restrict__ s,
                                              float* __restrict__ t) {
    __shared__ float xs[32][68];   // [k][i] (transposed so reads are float4)
    __shared__ float ws[32][68];   // [k][d]
    int h = blockIdx.y;
    int i0 = blockIdx.x * 64;
    int tid = threadIdx.x;
    int tx = tid & 15, ty = tid >> 4;
    const float* Wp = W + (size_t)h * FIN * DD;
    float acc[4][4] = {};
    for (int k0 = 0; k0 < FIN; k0 += 32) {
        #pragma unroll
        for (int e = 0; e < 8; ++e) {
            int lin = e * 256 + tid;
            int r = lin >> 5, c = lin & 31;          // r: i 0..63, c: k 0..31
            xs[c][r] = x[(size_t)(i0 + r) * FIN + k0 + c];
        }
        #pragma unroll
        for (int e = 0; e < 8; ++e) {
            int lin = e * 256 + tid;
            int r = lin >> 6, c = lin & 63;          // r: k 0..31, c: d 0..63
            ws[r][c] = Wp[(size_t)(k0 + r) * DD + c];
        }
        __syncthreads();
        #pragma unroll
        for (int kk = 0; kk < 32; ++kk) {
            float4 xv = *(const float4*)&xs[kk][ty * 4];
            float4 wv = *(const float4*)&ws[kk][tx * 4];
            float xa[4] = {xv.x, xv.y, xv.z, xv.w};
            float wa[4] = {wv.x, wv.y, wv.z, wv.w};
            #pragma unroll
            for (int ii = 0; ii < 4; ++ii)
                #pragma unroll
                for (int dd = 0; dd < 4; ++dd)
                    acc[ii][dd] += xa[ii] * wa[dd];
        }
        __syncthreads();
    }
    // epilogue: bf16 store + fused s,t (reduce over tx within 16-lane groups)
    float as[4], ad[4];
    #pragma unroll
    for (int dd = 0; dd < 4; ++dd) {
        as[dd] = a_src[h * DD + tx * 4 + dd];
        ad[dd] = a_dst[h * DD + tx * 4 + dd];
    }
    #pragma unroll
    for (int ii = 0; ii < 4; ++ii) {
        int i = i0 + ty * 4 + ii;
        float sp = acc[ii][0] * as[0] + acc[ii][1] * as[1] +
                   acc[ii][2] * as[2] + acc[ii][3] * as[3];
        float tp = acc[ii][0] * ad[0] + acc[ii][1] * ad[1] +
                   acc[ii][2] * ad[2] + acc[ii][3] * ad[3];
        #pragma unroll
        for (int off = 8; off; off >>= 1) {
            sp += __shfl_xor(sp, off);
            tp += __shfl_xor(tp, off);
        }
        if (tx == 0) {
            s[h * NN + i] = sp;
            t[h * NN + i] = tp;
        }
        ushort4 pk;
        pk.x = bf16rne(acc[ii][0]); pk.y = bf16rne(acc[ii][1]);
        pk.z = bf16rne(acc[ii][2]); pk.w = bf16rne(acc[ii][3]);
        *(ushort4*)&Whb[((size_t)h * NN + i) * DD + tx * 4] = pk;
    }
}

// ---------- Kernel 3: fused masked-softmax aggregation + ELU via MFMA ----------
// block = (i-tile of 64, head), 256 threads = 4 waves, each wave owns 16 rows.
__global__ __launch_bounds__(256) void k_agg(const ushort* __restrict__ Whb,
                                             const float* __restrict__ s,
                                             const float* __restrict__ t,
                                             const u64* __restrict__ bm,
                                             float* __restrict__ out) {
    __shared__ ushort Vt[64][72];   // [d][j], stride 72 bf16 = 144B (16B-mult, bank-spread)
    __shared__ float tls[64];
    __shared__ u64 bmls[64];
    int h = blockIdx.y;
    int i0 = blockIdx.x * 64;
    int tid = threadIdx.x;
    int w = tid >> 6, lane = tid & 63, lm = lane & 15, g = lane >> 4;
    int jp = tid & 31, c = tid >> 5;   // staging coords: j-pair, 8-d group
    const float LOG2E = 1.4426950408889634f;
    float s_i = s[h * NN + i0 + w * 16 + lm] * LOG2E;
    f32x4 acc[4] = {};
    float lacc = 0.f;
    u32* VtW = (u32*)&Vt[0][0];
    for (int jt = 0; jt < NN / 64; ++jt) {
        int j0 = jt * 64;
        // --- stage V tile transposed: Vt[d][j] = Whb[j0+j][d], pair-packed u32 writes ---
        uint4 va = *(const uint4*)(Whb + ((size_t)(h * NN + j0 + 2 * jp)) * DD + c * 8);
        uint4 vb = *(const uint4*)(Whb + ((size_t)(h * NN + j0 + 2 * jp + 1)) * DD + c * 8);
        const ushort* pa = (const ushort*)&va;
        const ushort* pb = (const ushort*)&vb;
        #pragma unroll
        for (int k = 0; k < 8; ++k)
            VtW[(c * 8 + k) * 36 + jp] = (u32)pa[k] | ((u32)pb[k] << 16);
        if (tid < 64) bmls[tid] = bm[(size_t)(i0 + tid) * 64 + jt];
        if (tid >= 192) tls[tid - 192] = t[h * NN + j0 + (tid - 192)] * LOG2E;
        __syncthreads();
        // --- weights in A-frag layout: row = lm, k = ks*32 + g*8 + e ---
        u64 bits = bmls[w * 16 + lm];
        #pragma unroll
        for (int ks = 0; ks < 2; ++ks) {
            int kb = ks * 32 + g * 8;
            u32 msk = (u32)(bits >> kb) & 0xffu;
            float wv[8];
            #pragma unroll
            for (int e = 0; e < 8; ++e) {
                float z = s_i + tls[kb + e];
                z = fmaxf(z, 0.2f * z);           // LeakyReLU (log2-domain, scale>0 commutes)
                float ex = exp2f(z);
                wv[e] = ((msk >> e) & 1u) ? ex : 0.f;
                lacc += wv[e];
            }
            short8 a;
            #pragma unroll
            for (int e = 0; e < 8; ++e) a[e] = (short)bf16rne(wv[e]);
            #pragma unroll
            for (int cf = 0; cf < 4; ++cf) {
                short8 b = *(const short8*)&Vt[cf * 16 + lm][kb];
                acc[cf] = __builtin_amdgcn_mfma_f32_16x16x32_bf16(a, b, acc[cf], 0, 0, 0);
            }
        }
        __syncthreads();
    }
    // --- l_i: sum the 4 j-groups; all lanes end with full sum for row lm ---
    lacc += __shfl_xor(lacc, 16);
    lacc += __shfl_xor(lacc, 32);
    // --- epilogue: C layout col=lm, row=g*4+reg; fetch l via shfl, normalize, ELU ---
    #pragma unroll
    for (int reg = 0; reg < 4; ++reg) {
        float lr = __shfl(lacc, g * 4 + reg);
        float inv = 1.f / lr;
        int i = i0 + w * 16 + g * 4 + reg;
        #pragma unroll
        for (int cf = 0; cf < 4; ++cf) {
            float u = acc[cf][reg] * inv;
            u = u > 0.f ? u : __expf(u) - 1.f;
            out[(size_t)i * (HH * DD) + h * DD + cf * 16 + lm] = u;
        }
    }
}

extern "C" void kernel_launch(void* const* d_in, const int* in_sizes, int n_in,
                              void* d_out, int out_size, void* d_ws, size_t ws_size,
                              hipStream_t stream) {
    const float* x     = (const float*)d_in[0];
    const int*   adj   = (const int*)d_in[1];
    const float* W     = (const float*)d_in[2];
    const float* a_src = (const float*)d_in[3];
    const float* a_dst = (const float*)d_in[4];
    float* out = (float*)d_out;

    char* ws = (char*)d_ws;
    ushort* Whb = (ushort*)ws;                                  // 4 MB bf16 [H][N][D]
    u64*    bm  = (u64*)(ws + (size_t)4 * 1024 * 1024);         // 2 MB
    float*  s   = (float*)(ws + (size_t)6 * 1024 * 1024);       // 128 KB
    float*  t   = (float*)(ws + (size_t)6 * 1024 * 1024 + 128 * 1024);

    k_bitpack<<<dim3(NN * NN / 256), dim3(256), 0, stream>>>(adj, bm);
    k_proj<<<dim3(NN / 64, HH), dim3(256), 0, stream>>>(x, W, a_src, a_dst, Whb, s, t);
    k_agg<<<dim3(NN / 64, HH), dim3(256), 0, stream>>>(Whb, s, t, bm, out);
}

// Round 3
// 135.896 us; speedup vs baseline: 4.9942x; 1.2684x over previous
//
#include <hip/hip_runtime.h>
#include <hip/hip_bf16.h>
#include <math.h>

#define NN 4096
#define FIN 512
#define HH 8
#define DD 64

typedef unsigned long long u64;
typedef unsigned int u32;
typedef float f32x4 __attribute__((ext_vector_type(4)));
typedef short short8 __attribute__((ext_vector_type(8)));

__device__ inline ushort bf16rne(float f) {
    u32 u = __float_as_uint(f);
    u += 0x7FFFu + ((u >> 16) & 1u);
    return (ushort)(u >> 16);
}

__device__ inline short bf16s(float f) {
    __hip_bfloat16 h = __float2bfloat16(f);
    return *(short*)&h;
}

// ---------- Kernel 1: bit-pack adjacency: bm[i][jw] (u64, bit j%64) ----------
__global__ __launch_bounds__(256) void k_bitpack(const int* __restrict__ adj,
                                                 u64* __restrict__ bm) {
    int tid = blockIdx.x * 256 + threadIdx.x;   // one thread per adj element
    int lane = threadIdx.x & 63;
    int v = adj[tid];
    u64 m = __ballot(v > 0);
    if (lane == 0) bm[tid >> 6] = m;
}

// ---------- Kernel 2: projection GEMM fp32 -> bf16 Whb + fused s,t ----------
__global__ __launch_bounds__(256) void k_proj(const float* __restrict__ x,
                                              const float* __restrict__ W,
                                              const float* __restrict__ a_src,
                                              const float* __restrict__ a_dst,
                                              ushort* __restrict__ Whb,
                                              float* __restrict__ s,
                                              float* __restrict__ t) {
    __shared__ float xs[32][68];   // [k][i]
    __shared__ float ws[32][68];   // [k][d]
    int h = blockIdx.y;
    int i0 = blockIdx.x * 64;
    int tid = threadIdx.x;
    int tx = tid & 15, ty = tid >> 4;
    const float* Wp = W + (size_t)h * FIN * DD;
    float acc[4][4] = {};
    for (int k0 = 0; k0 < FIN; k0 += 32) {
        #pragma unroll
        for (int e = 0; e < 8; ++e) {
            int lin = e * 256 + tid;
            int r = lin >> 5, c = lin & 31;
            xs[c][r] = x[(size_t)(i0 + r) * FIN + k0 + c];
        }
        #pragma unroll
        for (int e = 0; e < 8; ++e) {
            int lin = e * 256 + tid;
            int r = lin >> 6, c = lin & 63;
            ws[r][c] = Wp[(size_t)(k0 + r) * DD + c];
        }
        __syncthreads();
        #pragma unroll
        for (int kk = 0; kk < 32; ++kk) {
            float4 xv = *(const float4*)&xs[kk][ty * 4];
            float4 wv = *(const float4*)&ws[kk][tx * 4];
            float xa[4] = {xv.x, xv.y, xv.z, xv.w};
            float wa[4] = {wv.x, wv.y, wv.z, wv.w};
            #pragma unroll
            for (int ii = 0; ii < 4; ++ii)
                #pragma unroll
                for (int dd = 0; dd < 4; ++dd)
                    acc[ii][dd] += xa[ii] * wa[dd];
        }
        __syncthreads();
    }
    float as[4], ad[4];
    #pragma unroll
    for (int dd = 0; dd < 4; ++dd) {
        as[dd] = a_src[h * DD + tx * 4 + dd];
        ad[dd] = a_dst[h * DD + tx * 4 + dd];
    }
    #pragma unroll
    for (int ii = 0; ii < 4; ++ii) {
        int i = i0 + ty * 4 + ii;
        float sp = acc[ii][0] * as[0] + acc[ii][1] * as[1] +
                   acc[ii][2] * as[2] + acc[ii][3] * as[3];
        float tp = acc[ii][0] * ad[0] + acc[ii][1] * ad[1] +
                   acc[ii][2] * ad[2] + acc[ii][3] * ad[3];
        #pragma unroll
        for (int off = 8; off; off >>= 1) {
            sp += __shfl_xor(sp, off);
            tp += __shfl_xor(tp, off);
        }
        if (tx == 0) {
            s[h * NN + i] = sp;
            t[h * NN + i] = tp;
        }
        ushort4 pk;
        pk.x = bf16rne(acc[ii][0]); pk.y = bf16rne(acc[ii][1]);
        pk.z = bf16rne(acc[ii][2]); pk.w = bf16rne(acc[ii][3]);
        *(ushort4*)&Whb[((size_t)h * NN + i) * DD + tx * 4] = pk;
    }
}

// ---------- Kernel 3: partial masked-softmax aggregation via MFMA (j-split) ----------
// grid (NN/64, HH, js); block 256 = 4 waves, each wave owns 16 rows.
__global__ __launch_bounds__(256) void k_aggp(const ushort* __restrict__ Whb,
                                              const float* __restrict__ s,
                                              const float* __restrict__ t,
                                              const u64* __restrict__ bm,
                                              float* __restrict__ pacc,
                                              float* __restrict__ pl,
                                              int ntiles) {
    __shared__ ushort Vt[64][72];   // [d][j], stride 144B
    __shared__ float tls[64];
    __shared__ u64 bmls[64];
    int h = blockIdx.y;
    int i0 = blockIdx.x * 64;
    int z = blockIdx.z;
    int tid = threadIdx.x;
    int w = tid >> 6, lane = tid & 63, lm = lane & 15, g = lane >> 4;
    int jp = tid & 31, c = tid >> 5;
    const float LOG2E = 1.4426950408889634f;
    float s_i = s[h * NN + i0 + w * 16 + lm] * LOG2E;
    f32x4 acc[4] = {};
    f32x4 accl = {};
    short8 ones;
    #pragma unroll
    for (int e = 0; e < 8; ++e) ones[e] = (short)0x3F80;
    u32* VtW = (u32*)&Vt[0][0];
    int jt0 = z * ntiles;
    for (int jj = 0; jj < ntiles; ++jj) {
        int jt = jt0 + jj;
        int j0 = jt * 64;
        // --- stage V tile transposed (pair-packed u32 writes) ---
        uint4 va = *(const uint4*)(Whb + ((size_t)(h * NN + j0 + 2 * jp)) * DD + c * 8);
        uint4 vb = *(const uint4*)(Whb + ((size_t)(h * NN + j0 + 2 * jp + 1)) * DD + c * 8);
        const ushort* pa = (const ushort*)&va;
        const ushort* pb = (const ushort*)&vb;
        #pragma unroll
        for (int k = 0; k < 8; ++k)
            VtW[(c * 8 + k) * 36 + jp] = (u32)pa[k] | ((u32)pb[k] << 16);
        if (tid < 64) bmls[tid] = bm[(size_t)(i0 + tid) * 64 + jt];
        if (tid >= 192) tls[tid - 192] = t[h * NN + j0 + (tid - 192)] * LOG2E;
        __syncthreads();
        // --- weights in A-frag layout: row = lm, k = ks*32 + g*8 + e ---
        u64 bits = bmls[w * 16 + lm];
        #pragma unroll
        for (int ks = 0; ks < 2; ++ks) {
            int kb = ks * 32 + g * 8;
            u32 msk = (u32)(bits >> kb) & 0xffu;
            short8 a;
            #pragma unroll
            for (int e = 0; e < 8; ++e) {
                float z2 = s_i + tls[kb + e];
                z2 = fmaxf(z2, 0.2f * z2);        // LeakyReLU (log2-domain)
                float ex = exp2f(z2);
                a[e] = bf16s(((msk >> e) & 1u) ? ex : 0.f);
            }
            accl = __builtin_amdgcn_mfma_f32_16x16x32_bf16(a, ones, accl, 0, 0, 0);
            #pragma unroll
            for (int cf = 0; cf < 4; ++cf) {
                short8 b = *(const short8*)&Vt[cf * 16 + lm][kb];
                acc[cf] = __builtin_amdgcn_mfma_f32_16x16x32_bf16(a, b, acc[cf], 0, 0, 0);
            }
        }
        __syncthreads();
    }
    // --- store partials: C layout col=lm, row=g*4+reg ---
    size_t pbase = ((size_t)z * HH + h) * NN;
    #pragma unroll
    for (int reg = 0; reg < 4; ++reg) {
        int i = i0 + w * 16 + g * 4 + reg;
        if (lm == 0) pl[pbase + i] = accl[reg];
        #pragma unroll
        for (int cf = 0; cf < 4; ++cf)
            pacc[(pbase + i) * DD + cf * 16 + lm] = acc[cf][reg];
    }
}

// ---------- Kernel 4: combine partials, normalize, ELU ----------
__global__ __launch_bounds__(256) void k_comb(const float* __restrict__ pacc,
                                              const float* __restrict__ pl,
                                              float* __restrict__ out, int js) {
    int gid = blockIdx.x * 256 + threadIdx.x;   // H*N*16 threads, 4 d's each
    int dgi = gid & 15;
    int hn = gid >> 4;
    int h = hn >> 12, n = hn & (NN - 1);
    f32x4 acc = {};
    float l = 0.f;
    for (int zz = 0; zz < js; ++zz) {
        const f32x4* p = (const f32x4*)(pacc + ((size_t)zz * HH * NN + hn) * DD + dgi * 4);
        acc += *p;
        l += pl[(size_t)zz * HH * NN + hn];
    }
    float inv = 1.f / l;
    float r[4];
    #pragma unroll
    for (int dd = 0; dd < 4; ++dd) {
        float u = acc[dd] * inv;
        r[dd] = u > 0.f ? u : __expf(u) - 1.f;
    }
    *(float4*)&out[(size_t)n * (HH * DD) + h * DD + dgi * 4] =
        make_float4(r[0], r[1], r[2], r[3]);
}

extern "C" void kernel_launch(void* const* d_in, const int* in_sizes, int n_in,
                              void* d_out, int out_size, void* d_ws, size_t ws_size,
                              hipStream_t stream) {
    const float* x     = (const float*)d_in[0];
    const int*   adj   = (const int*)d_in[1];
    const float* W     = (const float*)d_in[2];
    const float* a_src = (const float*)d_in[3];
    const float* a_dst = (const float*)d_in[4];
    float* out = (float*)d_out;

    char* ws = (char*)d_ws;
    ushort* Whb = (ushort*)ws;                                  // 4 MB bf16 [H][N][D]
    u64*    bm  = (u64*)(ws + (size_t)4 * 1024 * 1024);         // 2 MB
    float*  s   = (float*)(ws + (size_t)6 * 1024 * 1024);       // 128 KB
    float*  t   = (float*)(ws + (size_t)6 * 1024 * 1024 + 128 * 1024);
    size_t pbase_off = (size_t)6 * 1024 * 1024 + 512 * 1024;

    // choose j-split so partials fit in ws
    size_t per = (size_t)HH * NN * DD * 4 + (size_t)HH * NN * 4;  // pacc + pl per split
    int js = 4;
    while (js > 1 && pbase_off + (size_t)js * (per + 4096) > ws_size) js >>= 1;
    float* pacc = (float*)(ws + pbase_off);                           // js * 8 MB
    float* pl   = (float*)(ws + pbase_off + (size_t)js * HH * NN * DD * 4);
    int ntiles = (NN / 64) / js;

    k_bitpack<<<dim3(NN * NN / 256), dim3(256), 0, stream>>>(adj, bm);
    k_proj<<<dim3(NN / 64, HH), dim3(256), 0, stream>>>(x, W, a_src, a_dst, Whb, s, t);
    k_aggp<<<dim3(NN / 64, HH, js), dim3(256), 0, stream>>>(Whb, s, t, bm, pacc, pl, ntiles);
    k_comb<<<dim3(HH * NN * 16 / 256), dim3(256), 0, stream>>>(pacc, pl, out, js);
}